// Round 1
// baseline (1940.040 us; speedup 1.0000x reference)
//
#include <hip/hip_runtime.h>
#include <hip/hip_bf16.h>
#include <math.h>

// Problem: b=4, n=4096, d=64.
// d_out layout (fp32, flat concat): [loss(1)] [pred_attn 4*4096*4096] [true_attn 4*4096*4096]
// d_ws layout (fp32): qb[1M] kb[1M] qf[2M] kf[2M]  (24 MB total)

#define B 4
#define N 4096
#define D 64
#define NROWS (B * N)                 // 16384
#define ATTN_ELEMS ((size_t)B * N * N)  // 67108864

// ---------------------------------------------------------------------------
// Kernel 1: projections + feature maps. One block (64 threads) per row.
// qb[row,e] = sum_d h[d] * Wq_base[e,d]; z = h @ W_mlp^T + b; q = [exp(z),exp(-z)]
// Also zeroes out[0] (loss accumulator).
// ---------------------------------------------------------------------------
__global__ __launch_bounds__(64) void proj_kernel(
    const float* __restrict__ hidden,
    const float* __restrict__ Wq_mlp, const float* __restrict__ bq_mlp,
    const float* __restrict__ Wk_mlp, const float* __restrict__ bk_mlp,
    const float* __restrict__ Wq_base, const float* __restrict__ Wk_base,
    float* __restrict__ qb, float* __restrict__ kb,
    float* __restrict__ qf, float* __restrict__ kf,
    float* __restrict__ out) {
  const int row = blockIdx.x;      // 0..16383
  const int e = threadIdx.x;       // 0..63

  if (row == 0 && e == 0) out[0] = 0.0f;  // zero loss accumulator

  __shared__ float h[D];
  h[e] = hidden[(size_t)row * D + e];
  __syncthreads();

  const float* wqb = Wq_base + e * D;
  const float* wkb = Wk_base + e * D;
  const float* wqm = Wq_mlp + e * D;
  const float* wkm = Wk_mlp + e * D;

  float aqb = 0.f, akb = 0.f;
  float zq = bq_mlp[e], zk = bk_mlp[e];
#pragma unroll
  for (int d = 0; d < D; ++d) {
    float hd = h[d];
    aqb += hd * wqb[d];
    akb += hd * wkb[d];
    zq += hd * wqm[d];
    zk += hd * wkm[d];
  }
  qb[(size_t)row * D + e] = aqb;
  kb[(size_t)row * D + e] = akb;
  qf[(size_t)row * 2 * D + e]     = expf(zq);
  qf[(size_t)row * 2 * D + D + e] = expf(-zq);
  kf[(size_t)row * 2 * D + e]     = expf(zk);
  kf[(size_t)row * 2 * D + D + e] = expf(-zk);
}

// ---------------------------------------------------------------------------
// Kernel 2: raw score matrices (both), written into d_out regions.
// Block = 64x64 output tile, 256 threads, 4x4 per-thread register tile with
// strided mapping (rows ty+16i, cols tx+16j). LDS staged with XOR float4
// swizzle so fragment reads are <=2-way bank aliased (free).
// true_raw = (qb @ kb^T) / 8 ; pred_raw = qf @ kf^T
// ---------------------------------------------------------------------------
__global__ __launch_bounds__(256) void scores_kernel(
    const float* __restrict__ qb, const float* __restrict__ kb,
    const float* __restrict__ qf, const float* __restrict__ kf,
    float* __restrict__ out) {
  const int bt = blockIdx.z;
  const int mt = blockIdx.y;
  const int nt = blockIdx.x;
  const int tid = threadIdx.x;
  const int tx = tid & 15, ty = tid >> 4;

  __shared__ float As[64 * 64];
  __shared__ float Bs[64 * 64];
  float4* As4 = (float4*)As;
  float4* Bs4 = (float4*)Bs;

  const size_t rowb = (size_t)bt * N;
  const int m0 = mt * 64, n0 = nt * 64;

  float* pred = out + 1;
  float* tru  = out + 1 + ATTN_ELEMS;

  float acc[4][4];

  // ---------------- phase 1: base scores, K = 64 ----------------
#pragma unroll
  for (int i = 0; i < 4; ++i)
#pragma unroll
    for (int j = 0; j < 4; ++j) acc[i][j] = 0.f;

  for (int v = tid; v < 1024; v += 256) {
    int r = v >> 4, c4 = v & 15;
    float4 av = ((const float4*)(qb + (rowb + m0 + r) * D))[c4];
    float4 bv = ((const float4*)(kb + (rowb + n0 + r) * D))[c4];
    As4[r * 16 + (c4 ^ (r & 15))] = av;
    Bs4[r * 16 + (c4 ^ (r & 15))] = bv;
  }
  __syncthreads();

#pragma unroll
  for (int k4 = 0; k4 < 16; ++k4) {
    float4 a[4], b[4];
#pragma unroll
    for (int i = 0; i < 4; ++i) a[i] = As4[(ty + 16 * i) * 16 + (k4 ^ ty)];
#pragma unroll
    for (int j = 0; j < 4; ++j) b[j] = Bs4[(tx + 16 * j) * 16 + (k4 ^ tx)];
#pragma unroll
    for (int i = 0; i < 4; ++i)
#pragma unroll
      for (int j = 0; j < 4; ++j)
        acc[i][j] += a[i].x * b[j].x + a[i].y * b[j].y +
                     a[i].z * b[j].z + a[i].w * b[j].w;
  }

#pragma unroll
  for (int i = 0; i < 4; ++i) {
    size_t row = rowb + m0 + ty + 16 * i;
#pragma unroll
    for (int j = 0; j < 4; ++j)
      tru[row * N + n0 + tx + 16 * j] = acc[i][j] * 0.125f;
  }

  // ---------------- phase 2: hedgehog scores, K = 128 ----------------
#pragma unroll
  for (int i = 0; i < 4; ++i)
#pragma unroll
    for (int j = 0; j < 4; ++j) acc[i][j] = 0.f;

  for (int kc = 0; kc < 128; kc += 64) {
    __syncthreads();
    for (int v = tid; v < 1024; v += 256) {
      int r = v >> 4, c4 = v & 15;
      float4 av = ((const float4*)(qf + (rowb + m0 + r) * 128 + kc))[c4];
      float4 bv = ((const float4*)(kf + (rowb + n0 + r) * 128 + kc))[c4];
      As4[r * 16 + (c4 ^ (r & 15))] = av;
      Bs4[r * 16 + (c4 ^ (r & 15))] = bv;
    }
    __syncthreads();
#pragma unroll
    for (int k4 = 0; k4 < 16; ++k4) {
      float4 a[4], b[4];
#pragma unroll
      for (int i = 0; i < 4; ++i) a[i] = As4[(ty + 16 * i) * 16 + (k4 ^ ty)];
#pragma unroll
      for (int j = 0; j < 4; ++j) b[j] = Bs4[(tx + 16 * j) * 16 + (k4 ^ tx)];
#pragma unroll
      for (int i = 0; i < 4; ++i)
#pragma unroll
        for (int j = 0; j < 4; ++j)
          acc[i][j] += a[i].x * b[j].x + a[i].y * b[j].y +
                       a[i].z * b[j].z + a[i].w * b[j].w;
    }
  }

#pragma unroll
  for (int i = 0; i < 4; ++i) {
    size_t row = rowb + m0 + ty + 16 * i;
#pragma unroll
    for (int j = 0; j < 4; ++j)
      pred[row * N + n0 + tx + 16 * j] = acc[i][j];
  }
}

// ---------------------------------------------------------------------------
// Kernel 3: in-place row softmax for both matrices + KD loss.
// One block (256 threads) per row; 16 elements/thread in registers.
// ---------------------------------------------------------------------------
__device__ __forceinline__ float block_reduce(float v, bool is_max, float* red) {
#pragma unroll
  for (int o = 32; o > 0; o >>= 1) {
    float other = __shfl_down(v, o);
    v = is_max ? fmaxf(v, other) : (v + other);
  }
  int w = threadIdx.x >> 6;
  __syncthreads();  // protect red from any previous use
  if ((threadIdx.x & 63) == 0) red[w] = v;
  __syncthreads();
  return is_max ? fmaxf(fmaxf(red[0], red[1]), fmaxf(red[2], red[3]))
                : (red[0] + red[1] + red[2] + red[3]);
}

__global__ __launch_bounds__(256) void softmax_loss_kernel(float* __restrict__ out) {
  const size_t r = blockIdx.x;  // 0..16383
  float* pred = out + 1 + r * N;
  float* tru  = out + 1 + ATTN_ELEMS + r * N;
  const int tid = threadIdx.x;

  __shared__ float red[4];

  float lt[16], lp[16];
#pragma unroll
  for (int i = 0; i < 16; ++i) {
    lt[i] = tru[tid + 256 * i];
    lp[i] = pred[tid + 256 * i];
  }

  float mt_ = -INFINITY, mp_ = -INFINITY;
#pragma unroll
  for (int i = 0; i < 16; ++i) {
    mt_ = fmaxf(mt_, lt[i]);
    mp_ = fmaxf(mp_, lp[i]);
  }
  const float MT = block_reduce(mt_, true, red);
  const float MP = block_reduce(mp_, true, red);

  float st = 0.f, sp = 0.f;
#pragma unroll
  for (int i = 0; i < 16; ++i) {
    lt[i] = expf(lt[i] - MT);
    st += lt[i];
    lp[i] = expf(lp[i] - MP);
    sp += lp[i];
  }
  const float ST = block_reduce(st, false, red);
  const float SP = block_reduce(sp, false, red);
  const float it_ = 1.f / ST, ip_ = 1.f / SP;

  float lloss = 0.f;
#pragma unroll
  for (int i = 0; i < 16; ++i) {
    float t = lt[i] * it_;
    float p = lp[i] * ip_;
    tru[tid + 256 * i] = t;
    pred[tid + 256 * i] = p;
    lloss -= t * logf(p + 1e-9f);
  }
  lloss = block_reduce(lloss, false, red);
  if (tid == 0) atomicAdd(out, lloss * (1.0f / (float)NROWS));
}

// ---------------------------------------------------------------------------
extern "C" void kernel_launch(void* const* d_in, const int* in_sizes, int n_in,
                              void* d_out, int out_size, void* d_ws, size_t ws_size,
                              hipStream_t stream) {
  const float* hidden  = (const float*)d_in[0];
  const float* Wq_mlp  = (const float*)d_in[1];
  const float* bq_mlp  = (const float*)d_in[2];
  const float* Wk_mlp  = (const float*)d_in[3];
  const float* bk_mlp  = (const float*)d_in[4];
  const float* Wq_base = (const float*)d_in[5];
  const float* Wk_base = (const float*)d_in[6];
  float* out = (float*)d_out;
  float* ws  = (float*)d_ws;

  float* qb = ws;                  // 1048576 floats
  float* kb = ws + 1048576;        // 1048576 floats
  float* qf = ws + 2097152;        // 2097152 floats
  float* kf = ws + 4194304;        // 2097152 floats  (24 MB total)

  proj_kernel<<<NROWS, 64, 0, stream>>>(hidden, Wq_mlp, bq_mlp, Wk_mlp, bk_mlp,
                                        Wq_base, Wk_base, qb, kb, qf, kf, out);
  scores_kernel<<<dim3(64, 64, B), 256, 0, stream>>>(qb, kb, qf, kf, out);
  softmax_loss_kernel<<<NROWS, 256, 0, stream>>>(out);
}

// Round 2
// 1046.457 us; speedup vs baseline: 1.8539x; 1.8539x over previous
//
#include <hip/hip_runtime.h>
#include <hip/hip_bf16.h>
#include <math.h>

// Problem: b=4, n=4096, d=64.
// d_out (fp32 concat): [loss(1)] [pred_attn 4*4096*4096] [true_attn 4*4096*4096]
//
// ws layout (ushort/bf16 unless noted), element offsets:
//   qbh 0        qbl 1048576   kbh 2097152   kbl 3145728     (each 4*4096*64)
//   qfh 4194304  qfl 6291456   kfh 8388608   kfl 10485760    (each 4*4096*128)
//   [12582912 ushorts = 24 MB] then float partials[16384]

#define B 4
#define N 4096
#define D 64
#define NROWS (B * N)
#define ATTN_ELEMS ((size_t)B * N * N)

typedef __attribute__((ext_vector_type(8))) short short8;   // 8 bf16 = 4 VGPRs
typedef __attribute__((ext_vector_type(4))) float float4v;  // MFMA C/D

typedef unsigned short ushort_t;

__device__ __forceinline__ void split_bf16(float x, ushort_t& hi, ushort_t& lo) {
  __hip_bfloat16 h = __float2bfloat16(x);
  float r = x - __bfloat162float(h);
  __hip_bfloat16 l = __float2bfloat16(r);
  hi = *(ushort_t*)&h;
  lo = *(ushort_t*)&l;
}

// ---------------------------------------------------------------------------
// Kernel 1: projections + feature maps + split-bf16. One block (64 thr) / row.
// ---------------------------------------------------------------------------
__global__ __launch_bounds__(64) void proj_kernel(
    const float* __restrict__ hidden,
    const float* __restrict__ Wq_mlp, const float* __restrict__ bq_mlp,
    const float* __restrict__ Wk_mlp, const float* __restrict__ bk_mlp,
    const float* __restrict__ Wq_base, const float* __restrict__ Wk_base,
    ushort_t* __restrict__ ws) {
  const int row = blockIdx.x;   // 0..16383
  const int e = threadIdx.x;    // 0..63

  ushort_t* qbh = ws;
  ushort_t* qbl = ws + 1048576;
  ushort_t* kbh = ws + 2097152;
  ushort_t* kbl = ws + 3145728;
  ushort_t* qfh = ws + 4194304;
  ushort_t* qfl = ws + 6291456;
  ushort_t* kfh = ws + 8388608;
  ushort_t* kfl = ws + 10485760;

  __shared__ float h[D];
  h[e] = hidden[(size_t)row * D + e];
  __syncthreads();

  const float* wqb = Wq_base + e * D;
  const float* wkb = Wk_base + e * D;
  const float* wqm = Wq_mlp + e * D;
  const float* wkm = Wk_mlp + e * D;

  float aqb = 0.f, akb = 0.f;
  float zq = bq_mlp[e], zk = bk_mlp[e];
#pragma unroll
  for (int d = 0; d < D; ++d) {
    float hd = h[d];
    aqb += hd * wqb[d];
    akb += hd * wkb[d];
    zq += hd * wqm[d];
    zk += hd * wkm[d];
  }

  const size_t rb = (size_t)row * D + e;       // base rows, stride 64
  const size_t rf = (size_t)row * 2 * D + e;   // feature rows, stride 128
  ushort_t hi, lo;
  split_bf16(aqb, hi, lo);        qbh[rb] = hi; qbl[rb] = lo;
  split_bf16(akb, hi, lo);        kbh[rb] = hi; kbl[rb] = lo;
  split_bf16(expf(zq), hi, lo);   qfh[rf] = hi; qfl[rf] = lo;
  split_bf16(expf(-zq), hi, lo);  qfh[rf + D] = hi; qfl[rf + D] = lo;
  split_bf16(expf(zk), hi, lo);   kfh[rf] = hi; kfl[rf] = lo;
  split_bf16(expf(-zk), hi, lo);  kfh[rf + D] = hi; kfl[rf + D] = lo;
}

// ---------------------------------------------------------------------------
// Kernel 2: both raw score matrices via split-bf16 MFMA.
// Block = 128x128 output tile, 256 thr = 4 waves; wave -> 64x64 quadrant as
// 4x4 grid of 16x16x32 MFMA tiles. acc += Ah*Bh + Ah*Bl + Al*Bh (fp32 C).
// LDS: 4 buffers of [128 rows][BK=32 + pad16] bf16 (stride 48 = 96 B, keeps
// 16B alignment; fragment reads spread evenly, 8 touches/bank).
// ---------------------------------------------------------------------------
#define BK 32
#define LSTRIDE 48  // bf16 elements; 96 B, multiple of 16 B

__global__ __launch_bounds__(256) void scores_kernel(
    const ushort_t* __restrict__ ws, float* __restrict__ out) {
  const ushort_t* qbh = ws;
  const ushort_t* qbl = ws + 1048576;
  const ushort_t* kbh = ws + 2097152;
  const ushort_t* kbl = ws + 3145728;
  const ushort_t* qfh = ws + 4194304;
  const ushort_t* qfl = ws + 6291456;
  const ushort_t* kfh = ws + 8388608;
  const ushort_t* kfl = ws + 10485760;

  __shared__ ushort_t sAh[128 * LSTRIDE];
  __shared__ ushort_t sAl[128 * LSTRIDE];
  __shared__ ushort_t sBh[128 * LSTRIDE];
  __shared__ ushort_t sBl[128 * LSTRIDE];

  const int bt = blockIdx.z;
  const int m0 = blockIdx.y * 128;
  const int n0 = blockIdx.x * 128;
  const int tid = threadIdx.x;
  const int lane = tid & 63;
  const int w = tid >> 6;
  const int qr = w >> 1, qc = w & 1;     // quadrant row/col (64 each)
  const int fr = lane & 15;              // fragment row within 16
  const int quad = lane >> 4;            // 0..3

  const size_t rowb = (size_t)bt * N;
  float* pred = out + 1;
  float* tru  = out + 1 + ATTN_ELEMS;

  // two phases: 0 = true (qb@kb^T, K=64, scale 1/8), 1 = pred (qf@kf^T, K=128)
#pragma unroll
  for (int phase = 0; phase < 2; ++phase) {
    const ushort_t* Ah = phase ? qfh : qbh;
    const ushort_t* Al = phase ? qfl : qbl;
    const ushort_t* Bh = phase ? kfh : kbh;
    const ushort_t* Bl = phase ? kfl : kbl;
    const int Krow = phase ? 128 : 64;
    const int nchunk = Krow / BK;
    const float scale = phase ? 1.0f : 0.125f;
    float* dst = phase ? pred : tru;

    float4v acc[4][4];
#pragma unroll
    for (int i = 0; i < 4; ++i)
#pragma unroll
      for (int j = 0; j < 4; ++j) acc[i][j] = (float4v)0.f;

    for (int ck = 0; ck < nchunk; ++ck) {
      const int kc = ck * BK;
      __syncthreads();  // previous compute / write-out done
      // stage 128x32 bf16 per buffer; 512 16B-units per buffer, 2 per thread
      for (int u = tid; u < 512; u += 256) {
        const int r = u >> 2;
        const int c8 = (u & 3) * 8;
        const size_t goffA = (size_t)(rowb + m0 + r) * Krow + kc + c8;
        const size_t goffB = (size_t)(rowb + n0 + r) * Krow + kc + c8;
        const int loff = r * LSTRIDE + c8;
        *(float4*)&sAh[loff] = *(const float4*)&Ah[goffA];
        *(float4*)&sAl[loff] = *(const float4*)&Al[goffA];
        *(float4*)&sBh[loff] = *(const float4*)&Bh[goffB];
        *(float4*)&sBl[loff] = *(const float4*)&Bl[goffB];
      }
      __syncthreads();

      short8 ah[4], al[4], bh[4], bl[4];
#pragma unroll
      for (int t = 0; t < 4; ++t) {
        const int ra = (qr * 64 + t * 16 + fr) * LSTRIDE + 8 * quad;
        const int rb = (qc * 64 + t * 16 + fr) * LSTRIDE + 8 * quad;
        ah[t] = *(const short8*)&sAh[ra];
        al[t] = *(const short8*)&sAl[ra];
        bh[t] = *(const short8*)&sBh[rb];
        bl[t] = *(const short8*)&sBl[rb];
      }
#pragma unroll
      for (int tm = 0; tm < 4; ++tm)
#pragma unroll
        for (int tn = 0; tn < 4; ++tn) {
          acc[tm][tn] = __builtin_amdgcn_mfma_f32_16x16x32_bf16(
              ah[tm], bh[tn], acc[tm][tn], 0, 0, 0);
          acc[tm][tn] = __builtin_amdgcn_mfma_f32_16x16x32_bf16(
              ah[tm], bl[tn], acc[tm][tn], 0, 0, 0);
          acc[tm][tn] = __builtin_amdgcn_mfma_f32_16x16x32_bf16(
              al[tm], bh[tn], acc[tm][tn], 0, 0, 0);
        }
    }

    // write-out: C row = quad*4+reg (m), col = fr (n) within each 16x16 tile
#pragma unroll
    for (int tm = 0; tm < 4; ++tm) {
      const int rbase = m0 + qr * 64 + tm * 16 + quad * 4;
#pragma unroll
      for (int tn = 0; tn < 4; ++tn) {
        const int c = n0 + qc * 64 + tn * 16 + fr;
        float4v v = acc[tm][tn];
#pragma unroll
        for (int reg = 0; reg < 4; ++reg)
          dst[(rowb + rbase + reg) * N + c] = v[reg] * scale;
      }
    }
  }
}

// ---------------------------------------------------------------------------
// Kernel 3: in-place row softmax for both matrices + per-block loss partial.
// ---------------------------------------------------------------------------
__device__ __forceinline__ float block_reduce(float v, bool is_max, float* red) {
#pragma unroll
  for (int o = 32; o > 0; o >>= 1) {
    float other = __shfl_down(v, o);
    v = is_max ? fmaxf(v, other) : (v + other);
  }
  int w = threadIdx.x >> 6;
  __syncthreads();
  if ((threadIdx.x & 63) == 0) red[w] = v;
  __syncthreads();
  return is_max ? fmaxf(fmaxf(red[0], red[1]), fmaxf(red[2], red[3]))
                : (red[0] + red[1] + red[2] + red[3]);
}

__global__ __launch_bounds__(256) void softmax_loss_kernel(
    float* __restrict__ out, float* __restrict__ partials) {
  const size_t r = blockIdx.x;  // 0..16383
  float* pred = out + 1 + r * N;
  float* tru  = out + 1 + ATTN_ELEMS + r * N;
  const int tid = threadIdx.x;

  __shared__ float red[4];

  float lt[16], lp[16];
#pragma unroll
  for (int i = 0; i < 16; ++i) {
    lt[i] = tru[tid + 256 * i];
    lp[i] = pred[tid + 256 * i];
  }

  float mt_ = -INFINITY, mp_ = -INFINITY;
#pragma unroll
  for (int i = 0; i < 16; ++i) {
    mt_ = fmaxf(mt_, lt[i]);
    mp_ = fmaxf(mp_, lp[i]);
  }
  const float MT = block_reduce(mt_, true, red);
  const float MP = block_reduce(mp_, true, red);

  float st = 0.f, sp = 0.f;
#pragma unroll
  for (int i = 0; i < 16; ++i) {
    lt[i] = expf(lt[i] - MT);
    st += lt[i];
    lp[i] = expf(lp[i] - MP);
    sp += lp[i];
  }
  const float ST = block_reduce(st, false, red);
  const float SP = block_reduce(sp, false, red);
  const float it_ = 1.f / ST, ip_ = 1.f / SP;

  float lloss = 0.f;
#pragma unroll
  for (int i = 0; i < 16; ++i) {
    float t = lt[i] * it_;
    float p = lp[i] * ip_;
    tru[tid + 256 * i] = t;
    pred[tid + 256 * i] = p;
    lloss -= t * logf(p + 1e-9f);
  }
  lloss = block_reduce(lloss, false, red);
  if (tid == 0) partials[r] = lloss;
}

// ---------------------------------------------------------------------------
// Kernel 4: reduce 16384 partials -> out[0] = mean.
// ---------------------------------------------------------------------------
__global__ __launch_bounds__(256) void reduce_loss_kernel(
    const float* __restrict__ partials, float* __restrict__ out) {
  const int tid = threadIdx.x;
  __shared__ float red[4];
  float s = 0.f;
  for (int i = tid; i < NROWS; i += 256) s += partials[i];
  s = block_reduce(s, false, red);
  if (tid == 0) out[0] = s * (1.0f / (float)NROWS);
}

// ---------------------------------------------------------------------------
extern "C" void kernel_launch(void* const* d_in, const int* in_sizes, int n_in,
                              void* d_out, int out_size, void* d_ws, size_t ws_size,
                              hipStream_t stream) {
  const float* hidden  = (const float*)d_in[0];
  const float* Wq_mlp  = (const float*)d_in[1];
  const float* bq_mlp  = (const float*)d_in[2];
  const float* Wk_mlp  = (const float*)d_in[3];
  const float* bk_mlp  = (const float*)d_in[4];
  const float* Wq_base = (const float*)d_in[5];
  const float* Wk_base = (const float*)d_in[6];
  float* out = (float*)d_out;
  ushort_t* ws = (ushort_t*)d_ws;
  float* partials = (float*)(ws + 12582912);  // after 24 MB of bf16 splits

  proj_kernel<<<NROWS, 64, 0, stream>>>(hidden, Wq_mlp, bq_mlp, Wk_mlp, bk_mlp,
                                        Wq_base, Wk_base, ws);
  scores_kernel<<<dim3(32, 32, B), 256, 0, stream>>>(ws, out);
  softmax_loss_kernel<<<NROWS, 256, 0, stream>>>(out, partials);
  reduce_loss_kernel<<<1, 256, 0, stream>>>(partials, out);
}